// Round 1
// 259.301 us; speedup vs baseline: 1.0553x; 1.0553x over previous
//
#include <hip/hip_runtime.h>

// ---------------------------------------------------------------------------
// MHA forward, fp32 I/O.  S=4096, D=1024, NH=16, HD=64.
// R13: attention LDS diet.  (1) P tile never touches LDS: QK^T output is
// repacked into the PV B-fragment in-register via packed bf16 +
// v_permlane32_swap_b32 (2 swaps / ks-slice); this also removes the
// mid-iter barrier (1 barrier/iter now).  (2) K/V tiles go linear [64][64]
// with XOR swizzle (elem ^= (row&7)<<3) on both staging writes and frag
// reads -> conflict-free phases (was 4-way at stride 72; 4.19M conflict
// cycles measured).  LDS traffic/wave-iter 28KB -> 20KB.  (3) proj3 V^T
// epilogue now transposes through LDS and stores coalesced 16B chunks
// (was 8B scatter at stride 8KB: ~8x write amplification).
// GEMM core unchanged from R12.
// ---------------------------------------------------------------------------

typedef unsigned short ushort_t;
typedef unsigned short ushort4v __attribute__((ext_vector_type(4)));
typedef unsigned short ushort8 __attribute__((ext_vector_type(8)));
typedef __bf16 bf16x8 __attribute__((ext_vector_type(8)));
typedef float f32x4 __attribute__((ext_vector_type(4)));
typedef float f32x16 __attribute__((ext_vector_type(16)));
typedef unsigned int uint4v __attribute__((ext_vector_type(4)));

#define SEQ 4096
#define DIM 1024
#define NH 16
#define HD 64
// 0.125 * log2(e): folded into Q projection so softmax uses exp2 directly
#define QSCALE 0.18033688011112042f

#define LSTR 40                    // GEMM LDS row stride (elems): bank-safe
#define ABUF (128 * LSTR)
#define BBUF (64 * LSTR)

__device__ inline ushort_t fcvt(float f) {           // native f32->bf16 RTNE
    return __builtin_bit_cast(ushort_t, (__bf16)f);
}
__device__ inline bf16x8 frag_of(ushort8 t) {
    return __builtin_bit_cast(bf16x8, t);
}
__device__ inline bf16x8 lds_frag(const ushort_t* p) {
    return frag_of(*(const ushort8*)p);
}
__device__ inline unsigned pk2(float a, float b) {   // packed bf16 pair
    return (unsigned)fcvt(a) | ((unsigned)fcvt(b) << 16);
}
// swap lanes 32-63 of a with lanes 0-31 of b (gfx950 cross-lane op)
__device__ inline void plswap(unsigned& a, unsigned& b) {
    asm("v_permlane32_swap_b32 %0, %1" : "+v"(a), "+v"(b));
}
// swizzled elem offset within a linear [64][64] bf16 LDS tile
__device__ inline int swz(int row, int col) {
    return row * 64 + (col ^ ((row & 7) << 3));
}

// ---------------------------------------------------------------------------
// Prep: f32 -> bf16 converts
// ---------------------------------------------------------------------------
__global__ __launch_bounds__(256) void cvt2(
    const float* __restrict__ s0, ushort_t* __restrict__ d0,
    const float* __restrict__ s1, ushort_t* __restrict__ d1, int n8)
{
    const float* s = blockIdx.y ? s1 : s0;
    ushort_t*    d = blockIdx.y ? d1 : d0;
    int i = blockIdx.x * 256 + threadIdx.x;
    if (i >= n8) return;
    const f32x4* sp = (const f32x4*)s + (size_t)i * 2;
    f32x4 a = sp[0], b = sp[1];
    ushort8 o;
    for (int k = 0; k < 4; ++k) { o[k] = fcvt(a[k]); o[k + 4] = fcvt(b[k]); }
    *((ushort8*)d + i) = o;
}

__global__ __launch_bounds__(256) void cvt4(
    const float* __restrict__ s0, ushort_t* __restrict__ d0,
    const float* __restrict__ s1, ushort_t* __restrict__ d1,
    const float* __restrict__ s2, ushort_t* __restrict__ d2,
    const float* __restrict__ s3, ushort_t* __restrict__ d3, int n8)
{
    const float* ss[4] = {s0, s1, s2, s3};
    ushort_t*    dd[4] = {d0, d1, d2, d3};
    const float* s = ss[blockIdx.y];
    ushort_t*    d = dd[blockIdx.y];
    int i = blockIdx.x * 256 + threadIdx.x;
    if (i >= n8) return;
    const f32x4* sp = (const f32x4*)s + (size_t)i * 2;
    f32x4 a = sp[0], b = sp[1];
    ushort8 o;
    for (int k = 0; k < 4; ++k) { o[k] = fcvt(a[k]); o[k + 4] = fcvt(b[k]); }
    *((ushort8*)d + i) = o;
}

// ---------------------------------------------------------------------------
// Pipelined GEMM core (unchanged from R12).
// Tile 128(M) x 64(N), BK=32, 256 thr = 4 waves 2x2; each wave 64x32 out
// as 4x2 tiles of 16x16x32.  Double-buffered LDS, register staging, one
// barrier per iter.
// ---------------------------------------------------------------------------
__device__ __attribute__((always_inline)) inline void gemm_core(
    const ushort_t* __restrict__ A, const ushort_t* __restrict__ W,
    int m0, int n0, int tid, f32x4 (&acc)[4][2], ushort_t* sA, ushort_t* sB)
{
    const int lane = tid & 63;
    const int quad = lane >> 4;
    const int l15  = lane & 15;
    const int wm   = (tid >> 6) >> 1;
    const int wn   = (tid >> 6) & 1;

    const int ar0 = tid >> 2;
    const int ar1 = (tid + 256) >> 2;
    const int ac  = (tid & 3) << 3;
    const int br  = tid >> 2;
    const ushort_t* Ag0 = A + (size_t)(m0 + ar0) * DIM + ac;
    const ushort_t* Ag1 = A + (size_t)(m0 + ar1) * DIM + ac;
    const ushort_t* Wg  = W + (size_t)(n0 + br) * DIM + ac;
    const int la0 = ar0 * LSTR + ac, la1 = ar1 * LSTR + ac, lb = br * LSTR + ac;

    *(ushort8*)(sA + la0) = *(const ushort8*)(Ag0);
    *(ushort8*)(sA + la1) = *(const ushort8*)(Ag1);
    *(ushort8*)(sB + lb)  = *(const ushort8*)(Wg);
    __syncthreads();

    for (int it = 0; it < DIM / 32; ++it) {
        const int cur = it & 1;
        const int ktn = (it + 1) * 32;
        ushort_t* aC = sA + cur * ABUF;
        ushort_t* bC = sB + cur * BBUF;

        ushort8 ga0, ga1, gb0;
        if (ktn < DIM) {
            ga0 = *(const ushort8*)(Ag0 + ktn);
            ga1 = *(const ushort8*)(Ag1 + ktn);
            gb0 = *(const ushort8*)(Wg + ktn);
        }

        bf16x8 af[4], bf[2];
        for (int i = 0; i < 4; ++i)
            af[i] = lds_frag(aC + (wm * 64 + i * 16 + l15) * LSTR + quad * 8);
        for (int j = 0; j < 2; ++j)
            bf[j] = lds_frag(bC + (wn * 32 + j * 16 + l15) * LSTR + quad * 8);
        for (int i = 0; i < 4; ++i)
            for (int j = 0; j < 2; ++j)
                acc[i][j] = __builtin_amdgcn_mfma_f32_16x16x32_bf16(
                    af[i], bf[j], acc[i][j], 0, 0, 0);

        if (ktn < DIM) {
            ushort_t* aN = sA + (cur ^ 1) * ABUF;
            ushort_t* bN = sB + (cur ^ 1) * BBUF;
            *(ushort8*)(aN + la0) = ga0;
            *(ushort8*)(aN + la1) = ga1;
            *(ushort8*)(bN + lb)  = gb0;
        }
        __syncthreads();
    }
}

// Fused Q/K/V projections: z = 0 (Q, scaled), 1 (K), 2 (V, transposed out).
// grid = (DIM/64, SEQ/128, 3) = (16, 32, 3) = 1536 blocks.
__global__ __launch_bounds__(256) void proj3(
    const ushort_t* __restrict__ Qb, const ushort_t* __restrict__ KVb,
    const ushort_t* __restrict__ qwb, const ushort_t* __restrict__ kwb,
    const ushort_t* __restrict__ vwb,
    const float* __restrict__ q_b, const float* __restrict__ k_b,
    const float* __restrict__ v_b,
    ushort_t* __restrict__ Qp, ushort_t* __restrict__ Kp,
    ushort_t* __restrict__ VpT)
{
    __shared__ __align__(16) ushort_t sA[2 * ABUF];
    __shared__ __align__(16) ushort_t sB[2 * BBUF];

    const int z = blockIdx.z;
    const ushort_t* A = z ? KVb : Qb;
    const ushort_t* W = (z == 0) ? qwb : (z == 1 ? kwb : vwb);
    const float* bias = (z == 0) ? q_b : (z == 1 ? k_b : v_b);
    const int tid = threadIdx.x;
    const int m0 = blockIdx.y * 128;
    const int n0 = blockIdx.x * 64;

    f32x4 acc[4][2] = {};
    gemm_core(A, W, m0, n0, tid, acc, sA, sB);

    const int lane = tid & 63, quad = lane >> 4, l15 = lane & 15;
    const int wm = (tid >> 6) >> 1, wn = (tid >> 6) & 1;

    if (z == 2) {
        // V^T epilogue: transpose 128x64 C-tile through LDS (sA is free
        // after gemm_core's final barrier), then coalesced 16B stores.
        const int TSTR = 136;                // row stride: 272B, 16B-aligned
        for (int j = 0; j < 2; ++j) {
            int col = wn * 32 + j * 16 + l15;           // tile-local n
            float bj = bias[n0 + col];
            for (int i = 0; i < 4; ++i) {
                int row = wm * 64 + i * 16 + quad * 4;  // tile-local m
                ushort4v o4;
                for (int r = 0; r < 4; ++r) o4[r] = fcvt(acc[i][j][r] + bj);
                *(ushort4v*)(sA + col * TSTR + row) = o4;
            }
        }
        __syncthreads();
        const int vrow = tid >> 2;           // 0..63  (V^T row = tile col)
        const int vc   = (tid & 3) << 3;     // 0,8,16,24
        ushort_t* dst = VpT + (size_t)(n0 + vrow) * SEQ + m0;
        const ushort_t* src = sA + vrow * TSTR;
        for (int k = 0; k < 4; ++k)
            *(ushort8*)(dst + vc + k * 32) = *(const ushort8*)(src + vc + k * 32);
    } else {
        const float scale = (z == 0) ? QSCALE : 1.0f;
        ushort_t* C = z ? Kp : Qp;
        for (int j = 0; j < 2; ++j) {
            int col = n0 + wn * 32 + j * 16 + l15;
            float bj = bias[col];
            for (int i = 0; i < 4; ++i) {
                int row = m0 + wm * 64 + i * 16 + quad * 4;
                for (int r = 0; r < 4; ++r)
                    C[(size_t)(row + r) * DIM + col] =
                        fcvt((acc[i][j][r] + bj) * scale);
            }
        }
    }
}

// O projection: f32 output.  grid = (16, 32).
__global__ __launch_bounds__(256) void gemm_out(
    const ushort_t* __restrict__ A, const ushort_t* __restrict__ W,
    const float* __restrict__ bias, float* __restrict__ C)
{
    __shared__ __align__(16) ushort_t sA[2 * ABUF];
    __shared__ __align__(16) ushort_t sB[2 * BBUF];

    const int tid = threadIdx.x;
    const int m0 = blockIdx.y * 128;
    const int n0 = blockIdx.x * 64;

    f32x4 acc[4][2] = {};
    gemm_core(A, W, m0, n0, tid, acc, sA, sB);

    const int lane = tid & 63, quad = lane >> 4, l15 = lane & 15;
    const int wm = (tid >> 6) >> 1, wn = (tid >> 6) & 1;
    for (int j = 0; j < 2; ++j) {
        int col = n0 + wn * 32 + j * 16 + l15;
        float bj = bias[col];
        for (int i = 0; i < 4; ++i) {
            int row = m0 + wm * 64 + i * 16 + quad * 4;
            for (int r = 0; r < 4; ++r)
                C[(size_t)(row + r) * DIM + col] = acc[i][j][r] + bj;
        }
    }
}

// ---------------------------------------------------------------------------
// Flash attention, R13.  32x32x16 MFMA, zero-shift softmax (Q pre-scaled
// by 0.125*log2e), register-prefetched double-buffered K/V staging.
//   - K/V tiles: linear [64][64] + XOR swizzle (row&7)<<3 -> conflict-free
//   - P tile stays in registers: pk2 + v_permlane32_swap_b32 builds the
//     PV B-fragment from the QK^T C-layout directly
//   - ONE barrier per kv-iter (P no longer reuses the K buffer)
// grid = (NH, SEQ/128) = (16, 32), 256 thr = 4 waves x 32 q rows.
// ---------------------------------------------------------------------------
#define TILE 4096                  // elems per 64x64 bf16 tile
#define BUFE (2 * TILE)            // K tile + V tile per buffer
__global__ __launch_bounds__(256, 2) void attn_kernel(
    const ushort_t* __restrict__ Q, const ushort_t* __restrict__ K,
    const ushort_t* __restrict__ VT, ushort_t* __restrict__ O)
{
    __shared__ __align__(16) ushort_t sB[2 * BUFE];   // 32768 B

    const int tid  = threadIdx.x;
    const int w    = tid >> 6;
    const int lane = tid & 63;
    const int l31  = lane & 31;
    const int hi   = lane >> 5;
    const int h    = blockIdx.x;
    const int q0   = blockIdx.y * 128 + w * 32;
    const int hHD  = h * HD;

    // staging: thread covers rows (tid>>3) and (tid>>3)+32, col chunk tid&7
    const int srow0 = tid >> 3;
    const int srow1 = srow0 + 32;
    const int sch   = (tid & 7) << 3;
    const ushort_t* Kg0 = K  + (size_t)srow0 * DIM + hHD + sch;
    const ushort_t* Kg1 = K  + (size_t)srow1 * DIM + hHD + sch;
    const ushort_t* Vg0 = VT + (size_t)(hHD + srow0) * SEQ + sch;
    const ushort_t* Vg1 = VT + (size_t)(hHD + srow1) * SEQ + sch;
    const int lk0 = swz(srow0, sch), lk1 = swz(srow1, sch);

    const ushort_t* qb = Q + (size_t)(q0 + l31) * DIM + hHD + hi * 8;
    bf16x8 qf[4];
    for (int ks = 0; ks < 4; ++ks)
        qf[ks] = frag_of(*(const ushort8*)(qb + ks * 16));

    *(ushort8*)(sB + lk0)        = *(const ushort8*)(Kg0);
    *(ushort8*)(sB + lk1)        = *(const ushort8*)(Kg1);
    *(ushort8*)(sB + TILE + lk0) = *(const ushort8*)(Vg0);
    *(ushort8*)(sB + TILE + lk1) = *(const ushort8*)(Vg1);
    __syncthreads();

    f32x16 oacc[2] = {};
    float l_i = 0.f;

    for (int it = 0; it < SEQ / 64; ++it) {
        const int cur = it & 1;
        const int kvn = (it + 1) * 64;
        ushort_t* bK = sB + cur * BUFE;
        ushort_t* bV = bK + TILE;

        // prefetch next kv tile into registers (lands at end of iter)
        ushort8 gk0, gk1, gv0, gv1;
        if (kvn < SEQ) {
            gk0 = *(const ushort8*)(Kg0 + (size_t)kvn * DIM);
            gk1 = *(const ushort8*)(Kg1 + (size_t)kvn * DIM);
            gv0 = *(const ushort8*)(Vg0 + kvn);
            gv1 = *(const ushort8*)(Vg1 + kvn);
        }

        bf16x8 kf[8], vf[8];
        for (int t = 0; t < 2; ++t)
            for (int ks = 0; ks < 4; ++ks) {
                int r = t * 32 + l31;
                kf[t * 4 + ks] = lds_frag(bK + swz(r, ks * 16 + hi * 8));
            }
        for (int dt = 0; dt < 2; ++dt)
            for (int ks = 0; ks < 4; ++ks) {
                int r = dt * 32 + l31;
                vf[ks * 2 + dt] = lds_frag(bV + swz(r, ks * 16 + hi * 8));
            }

        // S^T = K Q^T : lane l31 = q col, regs = kv rows
        f32x16 sacc[2] = {};
        for (int t = 0; t < 2; ++t)
            for (int ks = 0; ks < 4; ++ks)
                sacc[t] = __builtin_amdgcn_mfma_f32_32x32x16_bf16(
                    kf[t * 4 + ks], qf[ks], sacc[t], 0, 0, 0);

        float lp = 0.f;
        for (int t = 0; t < 2; ++t)
            for (int r = 0; r < 16; ++r) {
                float p = __builtin_amdgcn_exp2f(sacc[t][r]);
                sacc[t][r] = p;
                lp += p;
            }
        l_i += lp + __shfl_xor(lp, 32);

        // In-register P -> PV B-fragment.
        // C layout: sacc[t][r] = P[q=l31][kv = t*32+(r&3)+8*(r>>2)+4*hi]
        // B frag:   pf[j]      = P[q=l31][kv = ks*16+hi*8+j]
        // holder reg = (j&3) + 8*(ks&1) + 4*hi_dest; partner lane iff (j>>2)!=hi
        for (int ks = 0; ks < 4; ++ks) {
            const int t = ks >> 1, s8 = (ks & 1) * 8;
            unsigned p00 = pk2(sacc[t][s8 + 0], sacc[t][s8 + 1]);
            unsigned p01 = pk2(sacc[t][s8 + 2], sacc[t][s8 + 3]);
            unsigned p10 = pk2(sacc[t][s8 + 4], sacc[t][s8 + 5]);
            unsigned p11 = pk2(sacc[t][s8 + 6], sacc[t][s8 + 7]);
            plswap(p00, p10);   // p00 = words j0..1, p10 = words j4..5
            plswap(p01, p11);   // p01 = words j2..3, p11 = words j6..7
            uint4v wv; wv[0] = p00; wv[1] = p01; wv[2] = p10; wv[3] = p11;
            bf16x8 pf = __builtin_bit_cast(bf16x8, wv);
            for (int dt = 0; dt < 2; ++dt)
                oacc[dt] = __builtin_amdgcn_mfma_f32_32x32x16_bf16(
                    vf[ks * 2 + dt], pf, oacc[dt], 0, 0, 0);
        }

        if (kvn < SEQ) {
            ushort_t* nB = sB + (cur ^ 1) * BUFE;
            *(ushort8*)(nB + lk0)        = gk0;
            *(ushort8*)(nB + lk1)        = gk1;
            *(ushort8*)(nB + TILE + lk0) = gv0;
            *(ushort8*)(nB + TILE + lk1) = gv1;
        }
        __syncthreads();
    }

    float inv = 1.f / l_i;
    int qrow = q0 + l31;
    for (int dt = 0; dt < 2; ++dt)
        for (int g = 0; g < 4; ++g) {
            ushort4v o4;
            for (int r = 0; r < 4; ++r) o4[r] = fcvt(oacc[dt][g * 4 + r] * inv);
            *(ushort4v*)(O + (size_t)qrow * DIM + hHD + dt * 32 + g * 8 + hi * 4) = o4;
        }
}

// ---------------------------------------------------------------------------
extern "C" void kernel_launch(void* const* d_in, const int* in_sizes, int n_in,
                              void* d_out, int out_size, void* d_ws, size_t ws_size,
                              hipStream_t stream)
{
    const float* q   = (const float*)d_in[0];
    const float* kv  = (const float*)d_in[1];
    const float* q_w = (const float*)d_in[2];
    const float* q_b = (const float*)d_in[3];
    const float* k_w = (const float*)d_in[4];
    const float* k_b = (const float*)d_in[5];
    const float* v_w = (const float*)d_in[6];
    const float* v_b = (const float*)d_in[7];
    const float* o_w = (const float*)d_in[8];
    const float* o_b = (const float*)d_in[9];
    float* out = (float*)d_out;

    const size_t SD = (size_t)SEQ * DIM;
    const size_t WW = (size_t)DIM * DIM;
    ushort_t* Qp  = (ushort_t*)d_ws;          // bf16, pre-scaled by QSCALE
    ushort_t* Kp  = Qp + SD;
    ushort_t* VpT = Kp + SD;                  // V^T: [DIM][SEQ]
    ushort_t* AO  = VpT + SD;                 // attention out; aliases Qb
    ushort_t* Qb  = AO;                       // bf16(q) — dead before AO write
    ushort_t* KVb = AO + SD;
    ushort_t* qwb = KVb + SD;
    ushort_t* kwb = qwb + WW;
    ushort_t* vwb = kwb + WW;
    ushort_t* owb = vwb + WW;

    cvt2<<<dim3((unsigned)(SD / 8 / 256), 2), 256, 0, stream>>>(
        q, Qb, kv, KVb, (int)(SD / 8));
    cvt4<<<dim3((unsigned)(WW / 8 / 256), 4), 256, 0, stream>>>(
        q_w, qwb, k_w, kwb, v_w, vwb, o_w, owb, (int)(WW / 8));

    proj3<<<dim3(DIM / 64, SEQ / 128, 3), 256, 0, stream>>>(
        Qb, KVb, qwb, kwb, vwb, q_b, k_b, v_b, Qp, Kp, VpT);
    attn_kernel<<<dim3(NH, SEQ / 128), 256, 0, stream>>>(Qp, Kp, VpT, AO);
    gemm_out<<<dim3(DIM / 64, SEQ / 128), 256, 0, stream>>>(AO, owb, o_b, out);
}

// Round 3
// 245.343 us; speedup vs baseline: 1.1154x; 1.0569x over previous
//
#include <hip/hip_runtime.h>

// ---------------------------------------------------------------------------
// MHA forward, fp32 I/O.  S=4096, D=1024, NH=16, HD=64.
// R15 = R14 with the B-staging coverage bug fixed: each global_load_lds
// covers 8 rows (64 lanes x 8 elems), so a BN-row B tile needs BN/32
// loads per wave (R14 used BN/64 -> half the tile unstaged -> NaN).
// GEMM core: m97 pattern — global_load_lds width-16 staging, 128x128
// tile (proj3) / 128x64 (gemm_out), BK=64, double-buffered, one drain
// barrier per K-step, next-tile loads issued before the MFMA block.
// LDS linear (gl_lds requirement); frag-read bank conflicts removed by
// pre-swizzling the per-lane GLOBAL source chunk (chunk ^= row&7) and
// applying the same XOR on the read side (m173 trick).
// Attention unchanged from R13 (99.5 us).
// ---------------------------------------------------------------------------

typedef unsigned short ushort_t;
typedef unsigned short ushort4v __attribute__((ext_vector_type(4)));
typedef unsigned short ushort8 __attribute__((ext_vector_type(8)));
typedef __bf16 bf16x8 __attribute__((ext_vector_type(8)));
typedef float f32x4 __attribute__((ext_vector_type(4)));
typedef float f32x16 __attribute__((ext_vector_type(16)));
typedef unsigned int uint4v __attribute__((ext_vector_type(4)));

#define SEQ 4096
#define DIM 1024
#define NH 16
#define HD 64
// 0.125 * log2(e): folded into Q projection so softmax uses exp2 directly
#define QSCALE 0.18033688011112042f

__device__ inline ushort_t fcvt(float f) {           // native f32->bf16 RTNE
    return __builtin_bit_cast(ushort_t, (__bf16)f);
}
__device__ inline bf16x8 frag_of(ushort8 t) {
    return __builtin_bit_cast(bf16x8, t);
}
__device__ inline bf16x8 lds_frag(const ushort_t* p) {
    return frag_of(*(const ushort8*)p);
}
__device__ inline unsigned pk2(float a, float b) {   // packed bf16 pair
    return (unsigned)fcvt(a) | ((unsigned)fcvt(b) << 16);
}
// swap lanes 32-63 of a with lanes 0-31 of b (gfx950 cross-lane op)
__device__ inline void plswap(unsigned& a, unsigned& b) {
    asm("v_permlane32_swap_b32 %0, %1" : "+v"(a), "+v"(b));
}
// swizzled elem offset within a linear [64][64] bf16 LDS tile (attn)
__device__ inline int swz(int row, int col) {
    return row * 64 + (col ^ ((row & 7) << 3));
}
// async global->LDS, 16B per lane; LDS dest = wave-uniform base + lane*16
__device__ __attribute__((always_inline)) inline void gload16(
    const ushort_t* g, ushort_t* l)
{
    __builtin_amdgcn_global_load_lds(
        (const __attribute__((address_space(1))) void*)g,
        (__attribute__((address_space(3))) void*)l, 16, 0, 0);
}

// ---------------------------------------------------------------------------
// Prep: f32 -> bf16 converts
// ---------------------------------------------------------------------------
__global__ __launch_bounds__(256) void cvt2(
    const float* __restrict__ s0, ushort_t* __restrict__ d0,
    const float* __restrict__ s1, ushort_t* __restrict__ d1, int n8)
{
    const float* s = blockIdx.y ? s1 : s0;
    ushort_t*    d = blockIdx.y ? d1 : d0;
    int i = blockIdx.x * 256 + threadIdx.x;
    if (i >= n8) return;
    const f32x4* sp = (const f32x4*)s + (size_t)i * 2;
    f32x4 a = sp[0], b = sp[1];
    ushort8 o;
    for (int k = 0; k < 4; ++k) { o[k] = fcvt(a[k]); o[k + 4] = fcvt(b[k]); }
    *((ushort8*)d + i) = o;
}

__global__ __launch_bounds__(256) void cvt4(
    const float* __restrict__ s0, ushort_t* __restrict__ d0,
    const float* __restrict__ s1, ushort_t* __restrict__ d1,
    const float* __restrict__ s2, ushort_t* __restrict__ d2,
    const float* __restrict__ s3, ushort_t* __restrict__ d3, int n8)
{
    const float* ss[4] = {s0, s1, s2, s3};
    ushort_t*    dd[4] = {d0, d1, d2, d3};
    const float* s = ss[blockIdx.y];
    ushort_t*    d = dd[blockIdx.y];
    int i = blockIdx.x * 256 + threadIdx.x;
    if (i >= n8) return;
    const f32x4* sp = (const f32x4*)s + (size_t)i * 2;
    f32x4 a = sp[0], b = sp[1];
    ushort8 o;
    for (int k = 0; k < 4; ++k) { o[k] = fcvt(a[k]); o[k + 4] = fcvt(b[k]); }
    *((ushort8*)d + i) = o;
}

// ---------------------------------------------------------------------------
// R15 GEMM core.  Tile 128(M) x BN(N), BK=64, 256 thr = 4 waves as 2x2.
// Each wave: 64 x BN/2 output via acc[4][BN/32] tiles of 16x16x32.
// Staging: global_load_lds 16B/lane; one wave-load = 8 rows x 128B of
// contiguous LDS; A needs 4 loads/wave, B needs BN/32 loads/wave.
// LDS row->offset bijection: row r at elem offset r*64 (verified:
// r = wbase + i*8 + srow  ->  off = wbase*64 + i*512 + srow*64).
// Global source chunk pre-swizzled (c ^ row&7); read side applies the
// same XOR -> conflict-free frag reads on linear LDS.
// K-loop: issue next-tile gl_lds -> ds_read+MFMA current -> one barrier.
// ---------------------------------------------------------------------------
template<int BN>
__device__ __attribute__((always_inline)) inline void gemm_core2(
    const ushort_t* __restrict__ A, const ushort_t* __restrict__ W,
    int m0, int n0, int tid, f32x4 (&acc)[4][BN / 32], ushort_t* sLDS)
{
    constexpr int TA = 128 * 64;           // A tile elems (16 KB)
    constexpr int TB = BN * 64;            // B tile elems
    ushort_t* const aB0 = sLDS;
    ushort_t* const aB1 = sLDS + TA;
    ushort_t* const bB0 = sLDS + 2 * TA;
    ushort_t* const bB1 = sLDS + 2 * TA + TB;

    const int w    = tid >> 6;
    const int lane = tid & 63;
    const int quad = lane >> 4;
    const int l15  = lane & 15;
    const int wm   = w >> 1;
    const int wn   = w & 1;

    // staging lane geometry: row-in-group = lane>>3, source chunk swizzled
    const int srow = lane >> 3;                       // 0..7
    const int sch  = ((lane & 7) ^ srow) << 3;        // elems
    const ushort_t* Ag = A + (size_t)(m0 + w * 32 + srow) * DIM + sch;
    const ushort_t* Bg = W + (size_t)(n0 + w * (BN / 4) + srow) * DIM + sch;
    const int aOff = w * 2048;             // elems: wave covers 32 A-rows
    const int bOff = w * (BN * 16);        // elems: wave covers BN/4 B-rows

    // prologue: stage tile 0 into buffer 0
    for (int i = 0; i < 4; ++i)
        gload16(Ag + (size_t)(i * 8) * DIM, aB0 + aOff + i * 512);
    for (int i = 0; i < BN / 32; ++i)
        gload16(Bg + (size_t)(i * 8) * DIM, bB0 + bOff + i * 512);
    __syncthreads();

    const int cxor = l15 & 7;              // read-side chunk XOR
    for (int it = 0; it < DIM / 64; ++it) {
        const int cur = it & 1;
        ushort_t* aC = cur ? aB1 : aB0;
        ushort_t* bC = cur ? bB1 : bB0;
        ushort_t* aN = cur ? aB0 : aB1;
        ushort_t* bN = cur ? bB0 : bB1;

        // issue next tile's loads (drained at this iter's end barrier;
        // the MFMA block below hides most of the latency)
        if (it + 1 < DIM / 64) {
            const int k0 = (it + 1) * 64;
            for (int i = 0; i < 4; ++i)
                gload16(Ag + k0 + (size_t)(i * 8) * DIM, aN + aOff + i * 512);
            for (int i = 0; i < BN / 32; ++i)
                gload16(Bg + k0 + (size_t)(i * 8) * DIM, bN + bOff + i * 512);
        }

        for (int kk = 0; kk < 2; ++kk) {
            const int cq = kk * 4 + quad;
            bf16x8 af[4], bf[BN / 32];
            for (int i = 0; i < 4; ++i) {
                int row = wm * 64 + i * 16 + l15;
                af[i] = lds_frag(aC + row * 64 + ((cq ^ cxor) << 3));
            }
            for (int j = 0; j < BN / 32; ++j) {
                int row = wn * (BN / 2) + j * 16 + l15;
                bf[j] = lds_frag(bC + row * 64 + ((cq ^ cxor) << 3));
            }
            for (int i = 0; i < 4; ++i)
                for (int j = 0; j < BN / 32; ++j)
                    acc[i][j] = __builtin_amdgcn_mfma_f32_16x16x32_bf16(
                        af[i], bf[j], acc[i][j], 0, 0, 0);
        }
        __syncthreads();
    }
}

// Fused Q/K/V projections: z = 0 (Q, scaled), 1 (K), 2 (V, transposed out).
// grid = (DIM/128, SEQ/128, 3) = (8, 32, 3) = 768 blocks.
__global__ __launch_bounds__(256, 2) void proj3(
    const ushort_t* __restrict__ Qb, const ushort_t* __restrict__ KVb,
    const ushort_t* __restrict__ qwb, const ushort_t* __restrict__ kwb,
    const ushort_t* __restrict__ vwb,
    const float* __restrict__ q_b, const float* __restrict__ k_b,
    const float* __restrict__ v_b,
    ushort_t* __restrict__ Qp, ushort_t* __restrict__ Kp,
    ushort_t* __restrict__ VpT)
{
    __shared__ __align__(1024) ushort_t sLDS[32768];   // 64 KB

    const int z = blockIdx.z;
    const ushort_t* A = z ? KVb : Qb;
    const ushort_t* W = (z == 0) ? qwb : (z == 1 ? kwb : vwb);
    const float* bias = (z == 0) ? q_b : (z == 1 ? k_b : v_b);
    const int tid = threadIdx.x;
    const int m0 = blockIdx.y * 128;
    const int n0 = blockIdx.x * 128;

    f32x4 acc[4][4] = {};
    gemm_core2<128>(A, W, m0, n0, tid, acc, sLDS);

    const int lane = tid & 63, quad = lane >> 4, l15 = lane & 15;
    const int wm = (tid >> 6) >> 1, wn = (tid >> 6) & 1;

    if (z == 2) {
        // V^T epilogue: transpose 128x128 C-tile through LDS, then
        // coalesced stores (2 threads per V^T row, 64 elems each).
        const int TSTR = 136;                // row stride: 272B, 16B-aligned
        for (int j = 0; j < 4; ++j) {
            int col = wn * 64 + j * 16 + l15;           // tile-local n
            float bj = bias[n0 + col];
            for (int i = 0; i < 4; ++i) {
                int row = wm * 64 + i * 16 + quad * 4;  // tile-local m
                ushort4v o4;
                for (int r = 0; r < 4; ++r) o4[r] = fcvt(acc[i][j][r] + bj);
                *(ushort4v*)(sLDS + col * TSTR + row) = o4;
            }
        }
        __syncthreads();
        const int vrow = tid >> 1;           // 0..127  (V^T row = tile col)
        const int vc   = (tid & 1) * 64;
        ushort_t* dst = VpT + (size_t)(n0 + vrow) * SEQ + m0 + vc;
        const ushort_t* src = sLDS + vrow * TSTR + vc;
        for (int k = 0; k < 8; ++k)
            *(ushort8*)(dst + k * 8) = *(const ushort8*)(src + k * 8);
    } else {
        const float scale = (z == 0) ? QSCALE : 1.0f;
        ushort_t* C = z ? Kp : Qp;
        for (int j = 0; j < 4; ++j) {
            int col = n0 + wn * 64 + j * 16 + l15;
            float bj = bias[col];
            for (int i = 0; i < 4; ++i) {
                int row = m0 + wm * 64 + i * 16 + quad * 4;
                for (int r = 0; r < 4; ++r)
                    C[(size_t)(row + r) * DIM + col] =
                        fcvt((acc[i][j][r] + bj) * scale);
            }
        }
    }
}

// O projection: f32 output.  BN=64 -> grid (16, 32) = 512 blocks, 48 KB LDS.
__global__ __launch_bounds__(256, 2) void gemm_out(
    const ushort_t* __restrict__ A, const ushort_t* __restrict__ W,
    const float* __restrict__ bias, float* __restrict__ C)
{
    __shared__ __align__(1024) ushort_t sLDS[24576];   // 48 KB

    const int tid = threadIdx.x;
    const int m0 = blockIdx.y * 128;
    const int n0 = blockIdx.x * 64;

    f32x4 acc[4][2] = {};
    gemm_core2<64>(A, W, m0, n0, tid, acc, sLDS);

    const int lane = tid & 63, quad = lane >> 4, l15 = lane & 15;
    const int wm = (tid >> 6) >> 1, wn = (tid >> 6) & 1;
    for (int j = 0; j < 2; ++j) {
        int col = n0 + wn * 32 + j * 16 + l15;
        float bj = bias[col];
        for (int i = 0; i < 4; ++i) {
            int row = m0 + wm * 64 + i * 16 + quad * 4;
            for (int r = 0; r < 4; ++r)
                C[(size_t)(row + r) * DIM + col] = acc[i][j][r] + bj;
        }
    }
}

// ---------------------------------------------------------------------------
// Flash attention (unchanged from R13).  32x32x16 MFMA, zero-shift softmax
// (Q pre-scaled by 0.125*log2e), register-prefetched double-buffered K/V
// staging, XOR-swizzled [64][64] tiles, P kept in registers via
// pk2 + v_permlane32_swap_b32, ONE barrier per kv-iter.
// grid = (NH, SEQ/128) = (16, 32), 256 thr = 4 waves x 32 q rows.
// ---------------------------------------------------------------------------
#define TILE 4096                  // elems per 64x64 bf16 tile
#define BUFE (2 * TILE)            // K tile + V tile per buffer
__global__ __launch_bounds__(256, 2) void attn_kernel(
    const ushort_t* __restrict__ Q, const ushort_t* __restrict__ K,
    const ushort_t* __restrict__ VT, ushort_t* __restrict__ O)
{
    __shared__ __align__(16) ushort_t sB[2 * BUFE];   // 32768 B

    const int tid  = threadIdx.x;
    const int w    = tid >> 6;
    const int lane = tid & 63;
    const int l31  = lane & 31;
    const int hi   = lane >> 5;
    const int h    = blockIdx.x;
    const int q0   = blockIdx.y * 128 + w * 32;
    const int hHD  = h * HD;

    const int srow0 = tid >> 3;
    const int srow1 = srow0 + 32;
    const int sch   = (tid & 7) << 3;
    const ushort_t* Kg0 = K  + (size_t)srow0 * DIM + hHD + sch;
    const ushort_t* Kg1 = K  + (size_t)srow1 * DIM + hHD + sch;
    const ushort_t* Vg0 = VT + (size_t)(hHD + srow0) * SEQ + sch;
    const ushort_t* Vg1 = VT + (size_t)(hHD + srow1) * SEQ + sch;
    const int lk0 = swz(srow0, sch), lk1 = swz(srow1, sch);

    const ushort_t* qb = Q + (size_t)(q0 + l31) * DIM + hHD + hi * 8;
    bf16x8 qf[4];
    for (int ks = 0; ks < 4; ++ks)
        qf[ks] = frag_of(*(const ushort8*)(qb + ks * 16));

    *(ushort8*)(sB + lk0)        = *(const ushort8*)(Kg0);
    *(ushort8*)(sB + lk1)        = *(const ushort8*)(Kg1);
    *(ushort8*)(sB + TILE + lk0) = *(const ushort8*)(Vg0);
    *(ushort8*)(sB + TILE + lk1) = *(const ushort8*)(Vg1);
    __syncthreads();

    f32x16 oacc[2] = {};
    float l_i = 0.f;

    for (int it = 0; it < SEQ / 64; ++it) {
        const int cur = it & 1;
        const int kvn = (it + 1) * 64;
        ushort_t* bK = sB + cur * BUFE;
        ushort_t* bV = bK + TILE;

        ushort8 gk0, gk1, gv0, gv1;
        if (kvn < SEQ) {
            gk0 = *(const ushort8*)(Kg0 + (size_t)kvn * DIM);
            gk1 = *(const ushort8*)(Kg1 + (size_t)kvn * DIM);
            gv0 = *(const ushort8*)(Vg0 + kvn);
            gv1 = *(const ushort8*)(Vg1 + kvn);
        }

        bf16x8 kf[8], vf[8];
        for (int t = 0; t < 2; ++t)
            for (int ks = 0; ks < 4; ++ks) {
                int r = t * 32 + l31;
                kf[t * 4 + ks] = lds_frag(bK + swz(r, ks * 16 + hi * 8));
            }
        for (int dt = 0; dt < 2; ++dt)
            for (int ks = 0; ks < 4; ++ks) {
                int r = dt * 32 + l31;
                vf[ks * 2 + dt] = lds_frag(bV + swz(r, ks * 16 + hi * 8));
            }

        // S^T = K Q^T : lane l31 = q col, regs = kv rows
        f32x16 sacc[2] = {};
        for (int t = 0; t < 2; ++t)
            for (int ks = 0; ks < 4; ++ks)
                sacc[t] = __builtin_amdgcn_mfma_f32_32x32x16_bf16(
                    kf[t * 4 + ks], qf[ks], sacc[t], 0, 0, 0);

        float lp = 0.f;
        for (int t = 0; t < 2; ++t)
            for (int r = 0; r < 16; ++r) {
                float p = __builtin_amdgcn_exp2f(sacc[t][r]);
                sacc[t][r] = p;
                lp += p;
            }
        l_i += lp + __shfl_xor(lp, 32);

        // In-register P -> PV B-fragment (see R13 derivation).
        for (int ks = 0; ks < 4; ++ks) {
            const int t = ks >> 1, s8 = (ks & 1) * 8;
            unsigned p00 = pk2(sacc[t][s8 + 0], sacc[t][s8 + 1]);
            unsigned p01 = pk2(sacc[t][s8 + 2], sacc[t][s8 + 3]);
            unsigned p10 = pk2(sacc[t][s8 + 4], sacc[t][s8 + 5]);
            unsigned p11 = pk2(sacc[t][s8 + 6], sacc[t][s8 + 7]);
            plswap(p00, p10);
            plswap(p01, p11);
            uint4v wv; wv[0] = p00; wv[1] = p01; wv[2] = p10; wv[3] = p11;
            bf16x8 pf = __builtin_bit_cast(bf16x8, wv);
            for (int dt = 0; dt < 2; ++dt)
                oacc[dt] = __builtin_amdgcn_mfma_f32_32x32x16_bf16(
                    vf[ks * 2 + dt], pf, oacc[dt], 0, 0, 0);
        }

        if (kvn < SEQ) {
            ushort_t* nB = sB + (cur ^ 1) * BUFE;
            *(ushort8*)(nB + lk0)        = gk0;
            *(ushort8*)(nB + lk1)        = gk1;
            *(ushort8*)(nB + TILE + lk0) = gv0;
            *(ushort8*)(nB + TILE + lk1) = gv1;
        }
        __syncthreads();
    }

    float inv = 1.f / l_i;
    int qrow = q0 + l31;
    for (int dt = 0; dt < 2; ++dt)
        for (int g = 0; g < 4; ++g) {
            ushort4v o4;
            for (int r = 0; r < 4; ++r) o4[r] = fcvt(oacc[dt][g * 4 + r] * inv);
            *(ushort4v*)(O + (size_t)qrow * DIM + hHD + dt * 32 + g * 8 + hi * 4) = o4;
        }
}

// ---------------------------------------------------------------------------
extern "C" void kernel_launch(void* const* d_in, const int* in_sizes, int n_in,
                              void* d_out, int out_size, void* d_ws, size_t ws_size,
                              hipStream_t stream)
{
    const float* q   = (const float*)d_in[0];
    const float* kv  = (const float*)d_in[1];
    const float* q_w = (const float*)d_in[2];
    const float* q_b = (const float*)d_in[3];
    const float* k_w = (const float*)d_in[4];
    const float* k_b = (const float*)d_in[5];
    const float* v_w = (const float*)d_in[6];
    const float* v_b = (const float*)d_in[7];
    const float* o_w = (const float*)d_in[8];
    const float* o_b = (const float*)d_in[9];
    float* out = (float*)d_out;

    const size_t SD = (size_t)SEQ * DIM;
    const size_t WW = (size_t)DIM * DIM;
    ushort_t* Qp  = (ushort_t*)d_ws;          // bf16, pre-scaled by QSCALE
    ushort_t* Kp  = Qp + SD;
    ushort_t* VpT = Kp + SD;                  // V^T: [DIM][SEQ]
    ushort_t* AO  = VpT + SD;                 // attention out; aliases Qb
    ushort_t* Qb  = AO;                       // bf16(q) — dead before AO write
    ushort_t* KVb = AO + SD;
    ushort_t* qwb = KVb + SD;
    ushort_t* kwb = qwb + WW;
    ushort_t* vwb = kwb + WW;
    ushort_t* owb = vwb + WW;

    cvt2<<<dim3((unsigned)(SD / 8 / 256), 2), 256, 0, stream>>>(
        q, Qb, kv, KVb, (int)(SD / 8));
    cvt4<<<dim3((unsigned)(WW / 8 / 256), 4), 256, 0, stream>>>(
        q_w, qwb, k_w, kwb, v_w, vwb, o_w, owb, (int)(WW / 8));

    proj3<<<dim3(DIM / 128, SEQ / 128, 3), 256, 0, stream>>>(
        Qb, KVb, qwb, kwb, vwb, q_b, k_b, v_b, Qp, Kp, VpT);
    attn_kernel<<<dim3(NH, SEQ / 128), 256, 0, stream>>>(Qp, Kp, VpT, AO);
    gemm_out<<<dim3(DIM / 64, SEQ / 128), 256, 0, stream>>>(AO, owb, o_b, out);
}